// Round 7
// baseline (236.070 us; speedup 1.0000x reference)
//
#include <hip/hip_runtime.h>
#include <stdint.h>

// Ragged-batch MHA: N=11136 tokens, 16 segments (contiguous, batch_ids sorted),
// E=256, H=8, hd=32. Pipeline (3 dispatches, k_split FUSED away):
//   K2: qkv = x @ qkv_w^T + b. Reads x and qkv_w DIRECTLY in f32 and does the
//       RNE hi/lo bf16 split in-register (f32 bytes == hi+lo bf16 bytes, so
//       traffic-neutral; kills the 23.6MB xhi/xlo/whi/wlo round-trip and the
//       whole k_split dispatch). 3-MFMA split path, B tile in LDS, M=192/N=48,
//       A prefetched 2-deep in f32; XCD-affine swizzle. Q/K epilogue via LDS
//       transpose -> coalesced 16B stores. Block 0 computes segment offsets.
//   K3: flash attention, ALL-RESIDENT: 512-thread blocks (8 waves x 16 q-rows
//       = 128 tokens), grid (head, 87) = 696 blocks co-resident; K/V staged
//       per chunk shared by 8 waves. (Best measured structure.)
//   K4: out = attn @ o_w^T + o_b; ow read in f32, converted in staging.

#define N_TOK 11136
#define E 256
#define H 8
#define HD 32

typedef __attribute__((ext_vector_type(8))) __bf16 bf16x8;
typedef __attribute__((ext_vector_type(8))) unsigned short u16x8;
typedef __attribute__((ext_vector_type(4))) float f32x4;

__device__ __forceinline__ unsigned short f2bf(float f) {
  unsigned int u = __float_as_uint(f);
  u = (u + 0x7FFFu + ((u >> 16) & 1u)) >> 16;   // RNE
  return (unsigned short)u;
}
__device__ __forceinline__ float bf2f(unsigned short s) {
  return __uint_as_float(((unsigned int)s) << 16);
}
__device__ __forceinline__ bf16x8 ld8(const unsigned short* p) {
  return *(const bf16x8*)p;
}
__device__ __forceinline__ unsigned int cvtpk(float a, float b) {
  unsigned int r;
  asm("v_cvt_pk_bf16_f32 %0, %1, %2" : "=v"(r) : "v"(a), "v"(b));
  return r;
}
// 8 f32 -> (hi bf16x8, lo bf16x8), RNE both stages (same numerics as k_split).
__device__ __forceinline__ void f32_hilo8(const float4 a, const float4 b,
                                          bf16x8* hp, bf16x8* lp) {
  u16x8 h, l;
  const float ff[8] = {a.x, a.y, a.z, a.w, b.x, b.y, b.z, b.w};
#pragma unroll
  for (int j = 0; j < 8; ++j) {
    unsigned short hh = f2bf(ff[j]);
    h[j] = hh;
    l[j] = f2bf(ff[j] - bf2f(hh));
  }
  *hp = *(bf16x8*)&h;
  *lp = *(bf16x8*)&l;
}

// ---------------- K2: qkv projection (fused f32 input path) ----------------
// Tile M=192 (4 waves x 3 m-tiles of 16), N=48 (3 t-tiles), K=256 (whole).
// Virtual grid 16x64 = 1024 blocks; XCD-affine swizzle. Even colb blocks emit
// a head's full Q + K d0..15; odd colb emit K d16..31 + full V. Q/K go through
// LDS transpose -> coalesced 16B stores; V direct ushort4.
#define QK_BSTRIDE 264   // 256 + 8 pad
#define QSCALE (0.17677669529663687f * 1.4426950408889634f)   // 1/sqrt(32)*log2(e)
#define SQ_STR 36
#define SK_STR 20
__global__ __launch_bounds__(256, 3) void k_qkv(
    const float* __restrict__ x, const float* __restrict__ qw,
    const float* __restrict__ qkv_b, const int* __restrict__ ids,
    unsigned short* __restrict__ Qb, unsigned short* __restrict__ Kb,
    unsigned short* __restrict__ Vt, int* __restrict__ offs) {
  if (blockIdx.x == 0 && blockIdx.y == 0 && threadIdx.x < 17) {
    int b = threadIdx.x, lo = 0, hi = N_TOK;   // segment offsets for k_attn
    while (lo < hi) { int mid = (lo + hi) >> 1; if (ids[mid] < b) lo = mid + 1; else hi = mid; }
    offs[b] = lo;
  }
  int bid = blockIdx.x + 16 * blockIdx.y;
  int xcd = bid & 7;
  int j8 = bid >> 3;                      // 0..127
  int colb = j8 & 15;
  int tile = (j8 >> 4) * 8 + xcd;         // 0..63
  if (tile >= 58) return;                 // 58*192 == 11136
  int col0 = colb * 48;
  __shared__ __align__(16) unsigned short Bhi[48 * QK_BSTRIDE];
  __shared__ __align__(16) unsigned short Blo[48 * QK_BSTRIDE];
  int tid = threadIdx.x;
  int w = tid >> 6, lane = tid & 63, m = lane & 15, quad = lane >> 4;
  int rowb = tile * 192 + w * 48;

  // stage weight tile from f32, split hi/lo in-register: 48 rows x 256 cols
  {
    const float* wsrc = qw + (size_t)col0 * E;
#pragma unroll
    for (int i = 0; i < 6; ++i) {       // 48*32 8-elem chunks / 256 threads
      int flat = i * 256 + tid;
      int row = flat >> 5, c8 = flat & 31;
      const float* pp = wsrc + row * E + c8 * 8;
      float4 a = *(const float4*)pp, b = *(const float4*)(pp + 4);
      bf16x8 hv, lv;
      f32_hilo8(a, b, &hv, &lv);
      *(bf16x8*)(Bhi + row * QK_BSTRIDE + c8 * 8) = hv;
      *(bf16x8*)(Blo + row * QK_BSTRIDE + c8 * 8) = lv;
    }
  }
  __syncthreads();

  f32x4 acc[3][3] = {};
  float4 xa[3][2], xb[3][2];              // 2-deep f32 A prefetch
#pragma unroll
  for (int mt = 0; mt < 3; ++mt) {
    const float* rp = x + (size_t)(rowb + mt * 16 + m) * E + quad * 8;
    xa[mt][0] = *(const float4*)rp;        xa[mt][1] = *(const float4*)(rp + 4);
    xb[mt][0] = *(const float4*)(rp + 32); xb[mt][1] = *(const float4*)(rp + 36);
  }
  for (int kc = 0; kc < 8; ++kc) {
    bf16x8 ah[3], al[3];
#pragma unroll
    for (int mt = 0; mt < 3; ++mt) {
      f32_hilo8(xa[mt][0], xa[mt][1], &ah[mt], &al[mt]);   // convert at use
      xa[mt][0] = xb[mt][0]; xa[mt][1] = xb[mt][1];        // rotate pipeline
    }
    int kn = kc + 2; if (kn > 7) kn = 7;                   // prefetch kc+2
#pragma unroll
    for (int mt = 0; mt < 3; ++mt) {
      const float* rp = x + (size_t)(rowb + mt * 16 + m) * E + kn * 32 + quad * 8;
      xb[mt][0] = *(const float4*)rp;
      xb[mt][1] = *(const float4*)(rp + 4);
    }
    int ko = kc * 32 + quad * 8;
#pragma unroll
    for (int t = 0; t < 3; ++t) {
      bf16x8 bh = ld8(Bhi + (16 * t + m) * QK_BSTRIDE + ko);
      bf16x8 bl = ld8(Blo + (16 * t + m) * QK_BSTRIDE + ko);
#pragma unroll
      for (int mt = 0; mt < 3; ++mt) {
        acc[mt][t] = __builtin_amdgcn_mfma_f32_16x16x32_bf16(ah[mt], bh, acc[mt][t], 0, 0, 0);
        acc[mt][t] = __builtin_amdgcn_mfma_f32_16x16x32_bf16(ah[mt], bl, acc[mt][t], 0, 0, 0);
        acc[mt][t] = __builtin_amdgcn_mfma_f32_16x16x32_bf16(al[mt], bh, acc[mt][t], 0, 0, 0);
      }
    }
  }
  // ---- epilogue: Q/K via LDS transpose (Bhi reused as scratch), V direct ----
  __syncthreads();                         // retire all B-tile reads
  unsigned short* SQ = Bhi + w * (48 * SQ_STR);                     // 48x32/wave
  unsigned short* SK = Bhi + 4 * (48 * SQ_STR) + w * (48 * SK_STR); // 48x16
  int evenb = !(colb & 1);
  int hd = col0 / 96;
  if (evenb) {
#pragma unroll
    for (int t = 0; t < 2; ++t) {          // Q: d = 16t + m
      float bias = qkv_b[col0 + 16 * t + m];
#pragma unroll
      for (int mt = 0; mt < 3; ++mt)
#pragma unroll
        for (int r = 0; r < 4; ++r) {
          int row = mt * 16 + quad * 4 + r;
          SQ[row * SQ_STR + 16 * t + m] = f2bf((acc[mt][t][r] + bias) * QSCALE);
        }
    }
    {                                      // K d0..15: t=2
      float bias = qkv_b[col0 + 32 + m];
#pragma unroll
      for (int mt = 0; mt < 3; ++mt)
#pragma unroll
        for (int r = 0; r < 4; ++r) {
          int row = mt * 16 + quad * 4 + r;
          SK[row * SK_STR + m] = f2bf(acc[mt][2][r] + bias);
        }
    }
  } else {
    {                                      // K d16..31: t=0
      float bias = qkv_b[col0 + m];
#pragma unroll
      for (int mt = 0; mt < 3; ++mt)
#pragma unroll
        for (int r = 0; r < 4; ++r) {
          int row = mt * 16 + quad * 4 + r;
          SK[row * SK_STR + m] = f2bf(acc[mt][0][r] + bias);
        }
    }
#pragma unroll
    for (int t = 1; t < 3; ++t) {          // V: direct ushort4 stores
      int j = col0 + 16 * t + m;
      int hdv = j / 96;
      int rr = j - hdv * 96;
      int d = rr - 64;
      float bias = qkv_b[j];
#pragma unroll
      for (int mt = 0; mt < 3; ++mt) {
        int tokb = rowb + mt * 16 + quad * 4;
        ushort4 pk;
        pk.x = f2bf(acc[mt][t][0] + bias); pk.y = f2bf(acc[mt][t][1] + bias);
        pk.z = f2bf(acc[mt][t][2] + bias); pk.w = f2bf(acc[mt][t][3] + bias);
        *(ushort4*)(Vt + (size_t)(hdv * HD + d) * N_TOK + tokb) = pk;
      }
    }
  }
  asm volatile("s_waitcnt lgkmcnt(0)" ::: "memory");   // per-wave scratch RAW
  if (evenb) {
    int row16 = lane >> 2, chunk = lane & 3;           // Q: 1KB/instr stores
#pragma unroll
    for (int it = 0; it < 3; ++it) {
      int row = it * 16 + row16;
      int tok = rowb + row;
      bf16x8 v = ld8(SQ + row * SQ_STR + chunk * 8);
      *(bf16x8*)(Qb + ((size_t)hd * N_TOK + tok) * HD + chunk * 8) = v;
    }
  }
  {
    int kd0 = evenb ? 0 : 16;                          // K: 16B/token stores
    int row32 = lane >> 1, half = lane & 1;
#pragma unroll
    for (int it = 0; it < 2; ++it) {
      int row = it * 32 + row32;
      if (row < 48) {
        int tok = rowb + row;
        bf16x8 v = ld8(SK + row * SK_STR + half * 8);
        *(bf16x8*)(Kb + ((size_t)hd * N_TOK + tok) * HD + kd0 + half * 8) = v;
      }
    }
  }
}

// ---------------- K3: flash attention, all-resident 8-wave blocks ----------------
// 512 threads = 8 waves x 16 q-rows = 128 tokens/block; grid (head, 87) = 696
// blocks; LDS 35.8KB -> 4 blocks/CU fit -> whole grid co-resident. K/V staged
// per 64-key chunk shared by 8 waves (1 load + 1 ds_write per thread/chunk).
#define PSTRIDE 72
#define VSTR 72
__global__ __launch_bounds__(512, 4) void k_attn(
    const int* __restrict__ ids, const int* __restrict__ offs,
    const unsigned short* __restrict__ Qb, const unsigned short* __restrict__ Kb,
    const unsigned short* __restrict__ Vt,
    unsigned short* __restrict__ attnb) {
  __shared__ __align__(16) unsigned short Kl[2][64 * 32];    // [buf][key][d]
  __shared__ __align__(16) unsigned short Vl[2][32 * VSTR];  // [buf][d][key+pad]
  __shared__ __align__(16) unsigned short ldsP[8][16 * PSTRIDE];
  __shared__ int bred[16];
  int tid = threadIdx.x;
  int w = tid >> 6, lane = tid & 63;       // w in 0..7
  int m = lane & 15, quad = lane >> 4;
  int h = blockIdx.x;                      // x fastest -> XCD affinity by head
  int tok0 = blockIdx.y * 128;
  int q0 = tok0 + w * 16;
  unsigned short* P = ldsP[w];
  int tok = q0 + m;                        // this lane's q-row
  int b = ids[tok];
  int st = offs[b], en = offs[b + 1];
  int kmin = st, kmax = en, stM = st, enm = en;
#pragma unroll
  for (int d = 1; d <= 8; d <<= 1) {       // ranges depend only on m
    kmin = min(kmin, __shfl_xor(kmin, d));
    kmax = max(kmax, __shfl_xor(kmax, d));
    stM  = max(stM,  __shfl_xor(stM,  d));
    enm  = min(enm,  __shfl_xor(enm,  d));
  }
  if (lane == 0) { bred[w] = kmin; bred[8 + w] = kmax; }

  const unsigned short* Kbase = Kb + (size_t)h * N_TOK * HD;
  const unsigned short* Vbase = Vt + (size_t)h * HD * N_TOK;
  bf16x8 qf = ld8(Qb + (size_t)(h * N_TOK + tok) * HD + quad * 8);

  // staging role: waves 0-3 stage K (64 rows x 32 d), waves 4-7 stage V
  // (32 d-rows x 64 keys). One 16B load + one 16B ds_write per thread/chunk.
  bool isK = (tid < 256);
  int krow = tid >> 2, kgof = (tid & 3) * 8;         // K: key row, d offset
  int vt = tid - 256;
  int vrow = vt >> 3, vgof = (vt & 7) * 8;           // V: d row, key offset
  const unsigned short* gsrc = isK ? (Kbase + (size_t)krow * HD + kgof)
                                   : (Vbase + (size_t)vrow * N_TOK + vgof);
  size_t gmul = isK ? HD : 1;                        // * k0
  int ldsoff = isK ? (krow * 32 + kgof) : (vrow * VSTR + vgof);

  __syncthreads();                          // bred ready
  int kminB = bred[0], kmaxB = bred[8];
#pragma unroll
  for (int i = 1; i < 8; ++i) {
    kminB = min(kminB, bred[i]);
    kmaxB = max(kmaxB, bred[8 + i]);
  }
  int k0beg = kminB & ~63;                  // N_TOK % 64 == 0: chunks in-bounds

  // prologue: stage chunk 0 into buf 0
  bf16x8 g = ld8(gsrc + (size_t)k0beg * gmul);
  *(bf16x8*)((isK ? &Kl[0][0] : &Vl[0][0]) + ldsoff) = g;
  __syncthreads();

  float lsum = 0.f;
  f32x4 o0 = {}, o1 = {};
  int buf = 0;
  for (int k0 = k0beg; k0 < kmaxB; k0 += 64) {
    int k1 = (k0 + 64 < kmaxB) ? (k0 + 64) : k0;   // clamped uniform prefetch
    g = ld8(gsrc + (size_t)k1 * gmul);
    const unsigned short* Kc = &Kl[buf][0];
    const unsigned short* Vc = &Vl[buf][0];
    f32x4 s[4];
    __builtin_amdgcn_s_setprio(1);
#pragma unroll
    for (int i = 0; i < 4; ++i) {
      bf16x8 kf = ld8(Kc + (16 * i + m) * 32 + quad * 8);
      f32x4 z = {};
      s[i] = __builtin_amdgcn_mfma_f32_16x16x32_bf16(kf, qf, z, 0, 0, 0);
    }
    __builtin_amdgcn_s_setprio(0);
    bool interior = (k0 >= stM && k0 + 64 <= enm);  // per-wave (16 rows)
    int jb = k0 + quad * 4;
#pragma unroll
    for (int i = 0; i < 4; ++i) {
      float p[4];
#pragma unroll
      for (int r = 0; r < 4; ++r) {
        float sv = s[i][r];
        if (!interior) {
          int j = jb + 16 * i + r;
          sv = (j >= st && j < en) ? sv : -3e38f;   // v_exp(-3e38) == 0
        }
        float e;
        asm("v_exp_f32 %0, %1" : "=v"(e) : "v"(sv));
        p[r] = e;
      }
      lsum += (p[0] + p[1]) + (p[2] + p[3]);
      uint2 pk;
      pk.x = cvtpk(p[0], p[1]);            // RNE packed bf16 pair
      pk.y = cvtpk(p[2], p[3]);
      *(uint2*)(P + m * PSTRIDE + 16 * i + quad * 4) = pk;   // P^T[q=m][key]
    }
    __builtin_amdgcn_s_setprio(1);
#pragma unroll
    for (int c = 0; c < 2; ++c) {          // two 32-key sub-chunks
      bf16x8 pf  = ld8(P + m * PSTRIDE + 32 * c + quad * 8);        // B: P^T[q][k]
      bf16x8 vf0 = ld8(Vc + m * VSTR + 32 * c + quad * 8);          // A: V[d][k]
      bf16x8 vf1 = ld8(Vc + (16 + m) * VSTR + 32 * c + quad * 8);
      o0 = __builtin_amdgcn_mfma_f32_16x16x32_bf16(vf0, pf, o0, 0, 0, 0);  // d 0..15
      o1 = __builtin_amdgcn_mfma_f32_16x16x32_bf16(vf1, pf, o1, 0, 0, 0);  // d 16..31
    }
    __builtin_amdgcn_s_setprio(0);
    // stage next chunk into the other buffer (written this iter, read next)
    *(bf16x8*)((isK ? &Kl[buf ^ 1][0] : &Vl[buf ^ 1][0]) + ldsoff) = g;
    __syncthreads();
    buf ^= 1;
  }
  lsum += __shfl_xor(lsum, 16);
  lsum += __shfl_xor(lsum, 32);            // quads hold disjoint key partial sums
  float inv = 1.0f / lsum;                 // every q-row has >=1 valid key
  uint2 w0, w1;
  w0.x = cvtpk(o0[0] * inv, o0[1] * inv);
  w0.y = cvtpk(o0[2] * inv, o0[3] * inv);
  w1.x = cvtpk(o1[0] * inv, o1[1] * inv);
  w1.y = cvtpk(o1[2] * inv, o1[3] * inv);
  // O^T: col=q(lane&15)=this lane's tok; row=d=quad*4+r (+16 for o1)
  *(uint2*)(attnb + (size_t)tok * E + h * HD + quad * 4) = w0;
  *(uint2*)(attnb + (size_t)tok * E + h * HD + 16 + quad * 4) = w1;
}

// ---------------- K4: output projection (f32 weight path) ----------------
// Tile M=64 (4 waves x 1 m-tile), N=64 (4 t-tiles), K=256 whole.
// ow read in f32 and converted during LDS staging; A prefetched 2-deep.
__global__ __launch_bounds__(256, 4) void k_oproj(
    const unsigned short* __restrict__ attnb, const float* __restrict__ ow,
    const float* __restrict__ ob, float* __restrict__ out) {
  __shared__ __align__(16) unsigned short Bo[64 * QK_BSTRIDE];
  int tid = threadIdx.x;
  int w = tid >> 6, lane = tid & 63, m = lane & 15, quad = lane >> 4;
  int tok0 = blockIdx.x * 64, col0 = blockIdx.y * 64;
  {
    const float* osrc = ow + (size_t)col0 * E;
#pragma unroll
    for (int i = 0; i < 8; ++i) {         // 64*32 8-elem chunks / 256 threads
      int flat = i * 256 + tid;
      int row = flat >> 5, c8 = flat & 31;
      const float* pp = osrc + row * E + c8 * 8;
      float4 a = *(const float4*)pp, b = *(const float4*)(pp + 4);
      u16x8 hv;
      hv[0] = f2bf(a.x); hv[1] = f2bf(a.y); hv[2] = f2bf(a.z); hv[3] = f2bf(a.w);
      hv[4] = f2bf(b.x); hv[5] = f2bf(b.y); hv[6] = f2bf(b.z); hv[7] = f2bf(b.w);
      *(u16x8*)(Bo + row * QK_BSTRIDE + c8 * 8) = hv;
    }
  }
  __syncthreads();
  f32x4 acc[4] = {};
  int arow = tok0 + 16 * w + m;
  const unsigned short* abase = attnb + (size_t)arow * E + quad * 8;
  bf16x8 a1 = ld8(abase);                 // prefetch kc=0
  bf16x8 a2 = ld8(abase + 32);            // prefetch kc=1
  for (int kc = 0; kc < 8; ++kc) {
    bf16x8 a = a1;
    a1 = a2;
    int kn = kc + 2; if (kn > 7) kn = 7;
    a2 = ld8(abase + kn * 32);
    int ko = kc * 32 + quad * 8;
#pragma unroll
    for (int t = 0; t < 4; ++t) {
      bf16x8 b = ld8(Bo + (16 * t + m) * QK_BSTRIDE + ko);
      acc[t] = __builtin_amdgcn_mfma_f32_16x16x32_bf16(a, b, acc[t], 0, 0, 0);
    }
  }
#pragma unroll
  for (int t = 0; t < 4; ++t) {
    int j = col0 + 16 * t + m;
    float bias = ob[j];
#pragma unroll
    for (int r = 0; r < 4; ++r) {
      int tok = tok0 + 16 * w + quad * 4 + r;
      out[(size_t)tok * E + j] = acc[t][r] + bias;
    }
  }
}

extern "C" void kernel_launch(void* const* d_in, const int* in_sizes, int n_in,
                              void* d_out, int out_size, void* d_ws, size_t ws_size,
                              hipStream_t stream) {
  const float* x   = (const float*)d_in[0];
  const int*   ids = (const int*)d_in[1];
  const float* qw  = (const float*)d_in[2];
  const float* qb  = (const float*)d_in[3];
  const float* ow  = (const float*)d_in[4];
  const float* ob  = (const float*)d_in[5];
  float* out = (float*)d_out;

  char* p = (char*)d_ws;
  auto alloc = [&](size_t bytes) {
    char* r = p;
    p += (bytes + 255) & ~(size_t)255;
    return r;
  };
  int* offs = (int*)alloc(32 * sizeof(int));
  unsigned short* Qb  = (unsigned short*)alloc((size_t)N_TOK * E * 2);
  unsigned short* Kb  = (unsigned short*)alloc((size_t)N_TOK * E * 2);
  unsigned short* Vt  = (unsigned short*)alloc((size_t)N_TOK * E * 2);
  unsigned short* att = (unsigned short*)alloc((size_t)N_TOK * E * 2);

  k_qkv<<<dim3(16, 64), dim3(256), 0, stream>>>(x, qw, qb, ids, Qb, Kb, Vt, offs);
  k_attn<<<dim3(H, N_TOK / 128), dim3(512), 0, stream>>>(ids, offs, Qb, Kb, Vt, att);
  k_oproj<<<dim3(N_TOK / 64, E / 64), dim3(256), 0, stream>>>(att, ow, ob, out);
}

// Round 8
// 151.255 us; speedup vs baseline: 1.5607x; 1.5607x over previous
//
#include <hip/hip_runtime.h>
#include <stdint.h>

// Ragged-batch MHA: N=11136 tokens, 16 segments (contiguous, batch_ids sorted),
// E=256, H=8, hd=32. Pipeline:
//   K1: k_split — vectorized pre-split x->xhi/xlo, qkv_w->whi/wlo, o_w->owb;
//       block 0 also computes the 17 segment offsets (binary search).
//   K2: qkv = x @ qkv_w^T + b, 3-MFMA split path, all-bf16, B tile in LDS,
//       M=192/N=48, A register-prefetched 2-deep; XCD-affine swizzle.
//       EPILOGUE: Q/K transposed through per-wave LDS scratch (reusing the
//       dead Bhi tile) -> coalesced 16B stores.
//   K3: flash attention, ALL-RESIDENT: 512-thread blocks (8 waves x 16 q-rows
//       = 128 tokens), grid (head, 87) = 696 blocks co-resident; K/V staged
//       per chunk shared by 8 waves. (Best measured structure.)
//   K4: out = attn @ o_w^T + o_b, owb staged into LDS, A prefetched 2-deep.
// NOTE: this is an exact revert to the round-6-measured best (152.74 us).
// The k_split->k_qkv fusion (R7) regressed k_qkv 43->128.8 us: in-loop f32
// hi/lo conversion serialized load->MFMA; conversions stay in k_split.

#define N_TOK 11136
#define E 256
#define H 8
#define HD 32

typedef __attribute__((ext_vector_type(8))) __bf16 bf16x8;
typedef __attribute__((ext_vector_type(8))) unsigned short u16x8;
typedef __attribute__((ext_vector_type(4))) float f32x4;

__device__ __forceinline__ unsigned short f2bf(float f) {
  unsigned int u = __float_as_uint(f);
  u = (u + 0x7FFFu + ((u >> 16) & 1u)) >> 16;   // RNE
  return (unsigned short)u;
}
__device__ __forceinline__ float bf2f(unsigned short s) {
  return __uint_as_float(((unsigned int)s) << 16);
}
__device__ __forceinline__ bf16x8 ld8(const unsigned short* p) {
  return *(const bf16x8*)p;
}
__device__ __forceinline__ unsigned int cvtpk(float a, float b) {
  unsigned int r;
  asm("v_cvt_pk_bf16_f32 %0, %1, %2" : "=v"(r) : "v"(a), "v"(b));
  return r;
}

// ---------------- K1: vectorized hi/lo split + segment offsets ----------------
__global__ void k_split(const float* __restrict__ x, const float* __restrict__ qw,
                        const float* __restrict__ ow, const int* __restrict__ ids,
                        unsigned short* __restrict__ xhi, unsigned short* __restrict__ xlo,
                        unsigned short* __restrict__ whi, unsigned short* __restrict__ wlo,
                        unsigned short* __restrict__ owb, int* __restrict__ offs) {
  if (blockIdx.x == 0 && threadIdx.x < 17) {
    int b = threadIdx.x, lo = 0, hi = N_TOK;
    while (lo < hi) { int mid = (lo + hi) >> 1; if (ids[mid] < b) lo = mid + 1; else hi = mid; }
    offs[b] = lo;   // lower_bound(b); offs[0]=0, offs[16]=N
  }
  const int NX4 = N_TOK * E / 4;        // 712704
  const int NW4 = 3 * E * E / 4;        // 147456
  const int NO4 = E * E / 4;            // 16384
  int total = NX4 + NW4 + NO4;
  for (int i = blockIdx.x * blockDim.x + threadIdx.x; i < total;
       i += gridDim.x * blockDim.x) {
    if (i < NX4) {
      float4 v = ((const float4*)x)[i];
      ushort4 hv, lv;
      hv.x = f2bf(v.x); lv.x = f2bf(v.x - bf2f(hv.x));
      hv.y = f2bf(v.y); lv.y = f2bf(v.y - bf2f(hv.y));
      hv.z = f2bf(v.z); lv.z = f2bf(v.z - bf2f(hv.z));
      hv.w = f2bf(v.w); lv.w = f2bf(v.w - bf2f(hv.w));
      ((ushort4*)xhi)[i] = hv; ((ushort4*)xlo)[i] = lv;
    } else if (i < NX4 + NW4) {
      int j = i - NX4;
      float4 v = ((const float4*)qw)[j];
      ushort4 hv, lv;
      hv.x = f2bf(v.x); lv.x = f2bf(v.x - bf2f(hv.x));
      hv.y = f2bf(v.y); lv.y = f2bf(v.y - bf2f(hv.y));
      hv.z = f2bf(v.z); lv.z = f2bf(v.z - bf2f(hv.z));
      hv.w = f2bf(v.w); lv.w = f2bf(v.w - bf2f(hv.w));
      ((ushort4*)whi)[j] = hv; ((ushort4*)wlo)[j] = lv;
    } else {
      int j = i - NX4 - NW4;
      float4 v = ((const float4*)ow)[j];
      ushort4 hv;
      hv.x = f2bf(v.x); hv.y = f2bf(v.y); hv.z = f2bf(v.z); hv.w = f2bf(v.w);
      ((ushort4*)owb)[j] = hv;
    }
  }
}

// ---------------- K2: qkv projection ----------------
// Tile M=192 (4 waves x 3 m-tiles of 16), N=48 (3 t-tiles), K=256 (whole).
// Virtual grid 16x64 = 1024 blocks; XCD-affine swizzle: xcd=bid&7 sees all 16
// col-blocks of tiles {xcd, 8+xcd, ..., 56+xcd} -> per-XCD L2 footprint 2.4MB.
// Even colb blocks produce a head's full Q (32 d) + K d0..15; odd colb blocks
// produce K d16..31 + full V. Q/K go through LDS transpose -> coalesced 16B
// stores; V keeps direct ushort4 stores (16B-granular already).
#define QK_BSTRIDE 264   // 256 + 8 pad
#define QSCALE (0.17677669529663687f * 1.4426950408889634f)   // 1/sqrt(32)*log2(e)
#define SQ_STR 36        // scratch stride (shorts): 16 rows distinct banks
#define SK_STR 20
__global__ __launch_bounds__(256, 3) void k_qkv(
    const unsigned short* __restrict__ xhi, const unsigned short* __restrict__ xlo,
    const unsigned short* __restrict__ whi, const unsigned short* __restrict__ wlo,
    const float* __restrict__ qkv_b,
    unsigned short* __restrict__ Qb, unsigned short* __restrict__ Kb,
    unsigned short* __restrict__ Vt) {
  int bid = blockIdx.x + 16 * blockIdx.y;
  int xcd = bid & 7;
  int j8 = bid >> 3;                      // 0..127
  int colb = j8 & 15;
  int tile = (j8 >> 4) * 8 + xcd;         // 0..63
  if (tile >= 58) return;                 // 58*192 == 11136
  int col0 = colb * 48;
  __shared__ __align__(16) unsigned short Bhi[48 * QK_BSTRIDE];
  __shared__ __align__(16) unsigned short Blo[48 * QK_BSTRIDE];
  int tid = threadIdx.x;
  int w = tid >> 6, lane = tid & 63, m = lane & 15, quad = lane >> 4;
  int rowb = tile * 192 + w * 48;

  // stage pre-split weight tile: 48 rows x 256 cols, 16B copies
  {
    const u16x8* wh8 = (const u16x8*)(whi + (size_t)col0 * E);
    const u16x8* wl8 = (const u16x8*)(wlo + (size_t)col0 * E);
#pragma unroll
    for (int i = 0; i < 6; ++i) {       // 48*32 u16x8 chunks / 256 threads
      int flat = i * 256 + tid;
      int row = flat >> 5, c8 = flat & 31;
      *(u16x8*)(Bhi + row * QK_BSTRIDE + c8 * 8) = wh8[flat];
      *(u16x8*)(Blo + row * QK_BSTRIDE + c8 * 8) = wl8[flat];
    }
  }
  __syncthreads();

  f32x4 acc[3][3] = {};
  bf16x8 ah1[3], al1[3], ah2[3], al2[3];
#pragma unroll
  for (int mt = 0; mt < 3; ++mt) {      // prefetch kc=0 and kc=1
    const size_t ro = (size_t)(rowb + mt * 16 + m) * E + quad * 8;
    ah1[mt] = ld8(xhi + ro);       al1[mt] = ld8(xlo + ro);
    ah2[mt] = ld8(xhi + ro + 32);  al2[mt] = ld8(xlo + ro + 32);
  }
  for (int kc = 0; kc < 8; ++kc) {
    bf16x8 ah[3], al[3];
#pragma unroll
    for (int mt = 0; mt < 3; ++mt) {
      ah[mt] = ah1[mt]; al[mt] = al1[mt];     // rotate pipeline
      ah1[mt] = ah2[mt]; al1[mt] = al2[mt];
    }
    int kn = kc + 2; if (kn > 7) kn = 7;      // prefetch kc+2 (clamped)
    int kon = kn * 32 + quad * 8;
#pragma unroll
    for (int mt = 0; mt < 3; ++mt) {
      const size_t ro = (size_t)(rowb + mt * 16 + m) * E + kon;
      ah2[mt] = ld8(xhi + ro);
      al2[mt] = ld8(xlo + ro);
    }
    int ko = kc * 32 + quad * 8;
#pragma unroll
    for (int t = 0; t < 3; ++t) {
      bf16x8 bh = ld8(Bhi + (16 * t + m) * QK_BSTRIDE + ko);
      bf16x8 bl = ld8(Blo + (16 * t + m) * QK_BSTRIDE + ko);
#pragma unroll
      for (int mt = 0; mt < 3; ++mt) {
        acc[mt][t] = __builtin_amdgcn_mfma_f32_16x16x32_bf16(ah[mt], bh, acc[mt][t], 0, 0, 0);
        acc[mt][t] = __builtin_amdgcn_mfma_f32_16x16x32_bf16(ah[mt], bl, acc[mt][t], 0, 0, 0);
        acc[mt][t] = __builtin_amdgcn_mfma_f32_16x16x32_bf16(al[mt], bh, acc[mt][t], 0, 0, 0);
      }
    }
  }
  // ---- epilogue: Q/K via LDS transpose (Bhi reused as scratch), V direct ----
  // C layout: col = col0+16t+m, row(token) = rowb + mt*16 + quad*4 + r.
  __syncthreads();                         // retire all B-tile reads
  unsigned short* SQ = Bhi + w * (48 * SQ_STR);                 // 48x32 per wave
  unsigned short* SK = Bhi + 4 * (48 * SQ_STR) + w * (48 * SK_STR); // 48x16
  int evenb = !(colb & 1);
  int hd = col0 / 96;                      // head of this block's Q/K tiles
  if (evenb) {
    // Q: t=0,1 -> d = 16t + m (fold bias + logit scale)
#pragma unroll
    for (int t = 0; t < 2; ++t) {
      float bias = qkv_b[col0 + 16 * t + m];
#pragma unroll
      for (int mt = 0; mt < 3; ++mt)
#pragma unroll
        for (int r = 0; r < 4; ++r) {
          int row = mt * 16 + quad * 4 + r;
          SQ[row * SQ_STR + 16 * t + m] = f2bf((acc[mt][t][r] + bias) * QSCALE);
        }
    }
    // K d0..15: t=2
    {
      float bias = qkv_b[col0 + 32 + m];
#pragma unroll
      for (int mt = 0; mt < 3; ++mt)
#pragma unroll
        for (int r = 0; r < 4; ++r) {
          int row = mt * 16 + quad * 4 + r;
          SK[row * SK_STR + m] = f2bf(acc[mt][2][r] + bias);
        }
    }
  } else {
    // K d16..31: t=0
    {
      float bias = qkv_b[col0 + m];
#pragma unroll
      for (int mt = 0; mt < 3; ++mt)
#pragma unroll
        for (int r = 0; r < 4; ++r) {
          int row = mt * 16 + quad * 4 + r;
          SK[row * SK_STR + m] = f2bf(acc[mt][0][r] + bias);
        }
    }
    // V: t=1,2 direct stores (ushort4, unchanged path)
#pragma unroll
    for (int t = 1; t < 3; ++t) {
      int j = col0 + 16 * t + m;
      int hdv = j / 96;
      int rr = j - hdv * 96;
      int d = rr - 64;
      float bias = qkv_b[j];
#pragma unroll
      for (int mt = 0; mt < 3; ++mt) {
        int tokb = rowb + mt * 16 + quad * 4;
        ushort4 pk;
        pk.x = f2bf(acc[mt][t][0] + bias); pk.y = f2bf(acc[mt][t][1] + bias);
        pk.z = f2bf(acc[mt][t][2] + bias); pk.w = f2bf(acc[mt][t][3] + bias);
        *(ushort4*)(Vt + (size_t)(hdv * HD + d) * N_TOK + tokb) = pk;
      }
    }
  }
  // intra-wave LDS RAW fence (scratch regions are per-wave disjoint)
  asm volatile("s_waitcnt lgkmcnt(0)" ::: "memory");
  if (evenb) {
    // Q out: 16 tokens x 64B = 1KB contiguous per store instruction
    int row16 = lane >> 2, chunk = lane & 3;
#pragma unroll
    for (int it = 0; it < 3; ++it) {
      int row = it * 16 + row16;
      int tok = rowb + row;
      bf16x8 v = ld8(SQ + row * SQ_STR + chunk * 8);
      *(bf16x8*)(Qb + ((size_t)hd * N_TOK + tok) * HD + chunk * 8) = v;
    }
  }
  {
    // K out: 16B per token at its kd0 half
    int kd0 = evenb ? 0 : 16;
    int row32 = lane >> 1, half = lane & 1;
#pragma unroll
    for (int it = 0; it < 2; ++it) {
      int row = it * 32 + row32;
      if (row < 48) {
        int tok = rowb + row;
        bf16x8 v = ld8(SK + row * SK_STR + half * 8);
        *(bf16x8*)(Kb + ((size_t)hd * N_TOK + tok) * HD + kd0 + half * 8) = v;
      }
    }
  }
}

// ---------------- K3: flash attention, all-resident 8-wave blocks ----------------
// 512 threads = 8 waves x 16 q-rows = 128 tokens/block; grid (head, 87) = 696
// blocks; LDS 35.8KB -> 4 blocks/CU fit -> whole grid co-resident. K/V staged
// per 64-key chunk shared by 8 waves (1 load + 1 ds_write per thread/chunk).
#define PSTRIDE 72
#define VSTR 72
__global__ __launch_bounds__(512, 4) void k_attn(
    const int* __restrict__ ids, const int* __restrict__ offs,
    const unsigned short* __restrict__ Qb, const unsigned short* __restrict__ Kb,
    const unsigned short* __restrict__ Vt,
    unsigned short* __restrict__ attnb) {
  __shared__ __align__(16) unsigned short Kl[2][64 * 32];    // [buf][key][d]
  __shared__ __align__(16) unsigned short Vl[2][32 * VSTR];  // [buf][d][key+pad]
  __shared__ __align__(16) unsigned short ldsP[8][16 * PSTRIDE];
  __shared__ int bred[16];
  int tid = threadIdx.x;
  int w = tid >> 6, lane = tid & 63;       // w in 0..7
  int m = lane & 15, quad = lane >> 4;
  int h = blockIdx.x;                      // x fastest -> XCD affinity by head
  int tok0 = blockIdx.y * 128;
  int q0 = tok0 + w * 16;
  unsigned short* P = ldsP[w];
  int tok = q0 + m;                        // this lane's q-row
  int b = ids[tok];
  int st = offs[b], en = offs[b + 1];
  int kmin = st, kmax = en, stM = st, enm = en;
#pragma unroll
  for (int d = 1; d <= 8; d <<= 1) {       // ranges depend only on m
    kmin = min(kmin, __shfl_xor(kmin, d));
    kmax = max(kmax, __shfl_xor(kmax, d));
    stM  = max(stM,  __shfl_xor(stM,  d));
    enm  = min(enm,  __shfl_xor(enm,  d));
  }
  if (lane == 0) { bred[w] = kmin; bred[8 + w] = kmax; }

  const unsigned short* Kbase = Kb + (size_t)h * N_TOK * HD;
  const unsigned short* Vbase = Vt + (size_t)h * HD * N_TOK;
  bf16x8 qf = ld8(Qb + (size_t)(h * N_TOK + tok) * HD + quad * 8);

  // staging role: waves 0-3 stage K (64 rows x 32 d), waves 4-7 stage V
  // (32 d-rows x 64 keys). One 16B load + one 16B ds_write per thread/chunk.
  bool isK = (tid < 256);
  int krow = tid >> 2, kgof = (tid & 3) * 8;         // K: key row, d offset
  int vt = tid - 256;
  int vrow = vt >> 3, vgof = (vt & 7) * 8;           // V: d row, key offset
  const unsigned short* gsrc = isK ? (Kbase + (size_t)krow * HD + kgof)
                                   : (Vbase + (size_t)vrow * N_TOK + vgof);
  size_t gmul = isK ? HD : 1;                        // * k0
  int ldsoff = isK ? (krow * 32 + kgof) : (vrow * VSTR + vgof);

  __syncthreads();                          // bred ready
  int kminB = bred[0], kmaxB = bred[8];
#pragma unroll
  for (int i = 1; i < 8; ++i) {
    kminB = min(kminB, bred[i]);
    kmaxB = max(kmaxB, bred[8 + i]);
  }
  int k0beg = kminB & ~63;                  // N_TOK % 64 == 0: chunks in-bounds

  // prologue: stage chunk 0 into buf 0
  bf16x8 g = ld8(gsrc + (size_t)k0beg * gmul);
  *(bf16x8*)((isK ? &Kl[0][0] : &Vl[0][0]) + ldsoff) = g;
  __syncthreads();

  float lsum = 0.f;
  f32x4 o0 = {}, o1 = {};
  int buf = 0;
  for (int k0 = k0beg; k0 < kmaxB; k0 += 64) {
    int k1 = (k0 + 64 < kmaxB) ? (k0 + 64) : k0;   // clamped uniform prefetch
    g = ld8(gsrc + (size_t)k1 * gmul);
    const unsigned short* Kc = &Kl[buf][0];
    const unsigned short* Vc = &Vl[buf][0];
    f32x4 s[4];
    __builtin_amdgcn_s_setprio(1);
#pragma unroll
    for (int i = 0; i < 4; ++i) {
      bf16x8 kf = ld8(Kc + (16 * i + m) * 32 + quad * 8);
      f32x4 z = {};
      s[i] = __builtin_amdgcn_mfma_f32_16x16x32_bf16(kf, qf, z, 0, 0, 0);
    }
    __builtin_amdgcn_s_setprio(0);
    bool interior = (k0 >= stM && k0 + 64 <= enm);  // per-wave (16 rows)
    int jb = k0 + quad * 4;
#pragma unroll
    for (int i = 0; i < 4; ++i) {
      float p[4];
#pragma unroll
      for (int r = 0; r < 4; ++r) {
        float sv = s[i][r];
        if (!interior) {
          int j = jb + 16 * i + r;
          sv = (j >= st && j < en) ? sv : -3e38f;   // v_exp(-3e38) == 0
        }
        float e;
        asm("v_exp_f32 %0, %1" : "=v"(e) : "v"(sv));
        p[r] = e;
      }
      lsum += (p[0] + p[1]) + (p[2] + p[3]);
      uint2 pk;
      pk.x = cvtpk(p[0], p[1]);            // RNE packed bf16 pair
      pk.y = cvtpk(p[2], p[3]);
      *(uint2*)(P + m * PSTRIDE + 16 * i + quad * 4) = pk;   // P^T[q=m][key]
    }
    __builtin_amdgcn_s_setprio(1);
#pragma unroll
    for (int c = 0; c < 2; ++c) {          // two 32-key sub-chunks
      bf16x8 pf  = ld8(P + m * PSTRIDE + 32 * c + quad * 8);        // B: P^T[q][k]
      bf16x8 vf0 = ld8(Vc + m * VSTR + 32 * c + quad * 8);          // A: V[d][k]
      bf16x8 vf1 = ld8(Vc + (16 + m) * VSTR + 32 * c + quad * 8);
      o0 = __builtin_amdgcn_mfma_f32_16x16x32_bf16(vf0, pf, o0, 0, 0, 0);  // d 0..15
      o1 = __builtin_amdgcn_mfma_f32_16x16x32_bf16(vf1, pf, o1, 0, 0, 0);  // d 16..31
    }
    __builtin_amdgcn_s_setprio(0);
    // stage next chunk into the other buffer (written this iter, read next)
    *(bf16x8*)((isK ? &Kl[buf ^ 1][0] : &Vl[buf ^ 1][0]) + ldsoff) = g;
    __syncthreads();
    buf ^= 1;
  }
  lsum += __shfl_xor(lsum, 16);
  lsum += __shfl_xor(lsum, 32);            // quads hold disjoint key partial sums
  float inv = 1.0f / lsum;                 // every q-row has >=1 valid key
  uint2 w0, w1;
  w0.x = cvtpk(o0[0] * inv, o0[1] * inv);
  w0.y = cvtpk(o0[2] * inv, o0[3] * inv);
  w1.x = cvtpk(o1[0] * inv, o1[1] * inv);
  w1.y = cvtpk(o1[2] * inv, o1[3] * inv);
  // O^T: col=q(lane&15)=this lane's tok; row=d=quad*4+r (+16 for o1)
  *(uint2*)(attnb + (size_t)tok * E + h * HD + quad * 4) = w0;
  *(uint2*)(attnb + (size_t)tok * E + h * HD + 16 + quad * 4) = w1;
}

// ---------------- K4: output projection ----------------
// Tile M=64 (4 waves x 1 m-tile), N=64 (4 t-tiles), K=256 whole.
// Pre-converted owb copied into LDS; A-loads register-prefetched TWO kc ahead.
__global__ __launch_bounds__(256, 4) void k_oproj(
    const unsigned short* __restrict__ attnb, const unsigned short* __restrict__ owb,
    const float* __restrict__ ob, float* __restrict__ out) {
  __shared__ __align__(16) unsigned short Bo[64 * QK_BSTRIDE];
  int tid = threadIdx.x;
  int w = tid >> 6, lane = tid & 63, m = lane & 15, quad = lane >> 4;
  int tok0 = blockIdx.x * 64, col0 = blockIdx.y * 64;
  {
    const u16x8* o8 = (const u16x8*)(owb + (size_t)col0 * E);
#pragma unroll
    for (int i = 0; i < 8; ++i) {         // 64*32 u16x8 chunks / 256 threads
      int flat = i * 256 + tid;
      int row = flat >> 5, c8 = flat & 31;
      *(u16x8*)(Bo + row * QK_BSTRIDE + c8 * 8) = o8[flat];
    }
  }
  __syncthreads();
  f32x4 acc[4] = {};
  int arow = tok0 + 16 * w + m;
  const unsigned short* abase = attnb + (size_t)arow * E + quad * 8;
  bf16x8 a1 = ld8(abase);                 // prefetch kc=0
  bf16x8 a2 = ld8(abase + 32);            // prefetch kc=1
  for (int kc = 0; kc < 8; ++kc) {
    bf16x8 a = a1;
    a1 = a2;
    int kn = kc + 2; if (kn > 7) kn = 7;
    a2 = ld8(abase + kn * 32);
    int ko = kc * 32 + quad * 8;
#pragma unroll
    for (int t = 0; t < 4; ++t) {
      bf16x8 b = ld8(Bo + (16 * t + m) * QK_BSTRIDE + ko);
      acc[t] = __builtin_amdgcn_mfma_f32_16x16x32_bf16(a, b, acc[t], 0, 0, 0);
    }
  }
#pragma unroll
  for (int t = 0; t < 4; ++t) {
    int j = col0 + 16 * t + m;
    float bias = ob[j];
#pragma unroll
    for (int r = 0; r < 4; ++r) {
      int tok = tok0 + 16 * w + quad * 4 + r;
      out[(size_t)tok * E + j] = acc[t][r] + bias;
    }
  }
}

extern "C" void kernel_launch(void* const* d_in, const int* in_sizes, int n_in,
                              void* d_out, int out_size, void* d_ws, size_t ws_size,
                              hipStream_t stream) {
  const float* x   = (const float*)d_in[0];
  const int*   ids = (const int*)d_in[1];
  const float* qw  = (const float*)d_in[2];
  const float* qb  = (const float*)d_in[3];
  const float* ow  = (const float*)d_in[4];
  const float* ob  = (const float*)d_in[5];
  float* out = (float*)d_out;

  char* p = (char*)d_ws;
  auto alloc = [&](size_t bytes) {
    char* r = p;
    p += (bytes + 255) & ~(size_t)255;
    return r;
  };
  int* offs = (int*)alloc(32 * sizeof(int));
  unsigned short* xhi = (unsigned short*)alloc((size_t)N_TOK * E * 2);
  unsigned short* xlo = (unsigned short*)alloc((size_t)N_TOK * E * 2);
  unsigned short* whi = (unsigned short*)alloc((size_t)3 * E * E * 2);
  unsigned short* wlo = (unsigned short*)alloc((size_t)3 * E * E * 2);
  unsigned short* owb = (unsigned short*)alloc((size_t)E * E * 2);
  unsigned short* Qb  = (unsigned short*)alloc((size_t)N_TOK * E * 2);
  unsigned short* Kb  = (unsigned short*)alloc((size_t)N_TOK * E * 2);
  unsigned short* Vt  = (unsigned short*)alloc((size_t)N_TOK * E * 2);
  unsigned short* att = (unsigned short*)alloc((size_t)N_TOK * E * 2);

  k_split<<<dim3(1712), dim3(256), 0, stream>>>(x, qw, ow, ids, xhi, xlo, whi, wlo, owb, offs);
  k_qkv<<<dim3(16, 64), dim3(256), 0, stream>>>(xhi, xlo, whi, wlo, qb, Qb, Kb, Vt);
  k_attn<<<dim3(H, N_TOK / 128), dim3(512), 0, stream>>>(ids, offs, Qb, Kb, Vt, att);
  k_oproj<<<dim3(N_TOK / 64, E / 64), dim3(256), 0, stream>>>(att, owb, ob, out);
}